// Round 12
// baseline (72.381 us; speedup 1.0000x reference)
//
#include <hip/hip_runtime.h>
#include <stdint.h>

using bf16x8 = __attribute__((ext_vector_type(8))) __bf16;
using f32x4v = __attribute__((ext_vector_type(4))) float;
using f32x2v = __attribute__((ext_vector_type(2))) float;

__device__ __forceinline__ unsigned int f2bf(float f) {
  unsigned int u = __float_as_uint(f);
  return (u + 0x7FFFu + ((u >> 16) & 1u)) >> 16;  // RNE f32->bf16
}

// =====================================================================
// k0b: codebook f32 [1024][256] -> bf16 MFMA fragment order, 64-code
// chunks (32 KB) with QUARTER-major sub-order (16 codes = 8 KB):
//   addr = (code>>6)*32768 + ((code>>4)&3)*8192 + kk*1024
//          + (g*16 + (code&15))*16 + j*2
// thread l covers ch l*4..+3: kk=l>>3, g=(l>>1)&3, byte j=(l&1)*8.
// hn = +0.5||e||^2 (negated at k1's LDS copy).
// =====================================================================
__global__ __launch_bounds__(64) void k0b_cb(const float* __restrict__ cb,
                                             char* __restrict__ cbb,
                                             float* __restrict__ hn) {
  const int code = blockIdx.x, l = threadIdx.x;
  const float4 v = *(const float4*)(cb + code * 256 + l * 4);
  float ss = v.x * v.x + v.y * v.y + v.z * v.z + v.w * v.w;
  uint2 p;
  p.x = f2bf(v.x) | (f2bf(v.y) << 16);
  p.y = f2bf(v.z) | (f2bf(v.w) << 16);
  const int addr = ((code >> 6) << 15) + (((code >> 4) & 3) << 13) +
                   ((l >> 3) << 10) +
                   (((((l >> 1) & 3) << 4) + (code & 15)) << 4) + (l & 1) * 8;
  *(uint2*)(cbb + addr) = p;
#pragma unroll
  for (int s = 32; s; s >>= 1) ss += __shfl_down(ss, s, 64);
  if (l == 0) hn[code] = 0.5f * ss;
}

// =====================================================================
// k1_fused: 1024 blocks x 256 thr (4 waves), block = 64 rows.
// ALL waves share the A panel (M=64, 32 frags = 128 VGPR in regs);
// wave wv owns EXCLUSIVE 16-code quarter of each 64-code chunk =>
// barrier-free main loop (own-wave vmcnt only), B read exactly once.
// Per chunk/wave: 8 ds_read_b128 + 32 MFMA (4:1).
//  - packed (score&~1023)|(1023-col) argmax (R11-verified)
//  - hn folded into MFMA C-init
//  - cross-quarter winner: lv[4][64] packed max after loop
// LDS map (70976 B, 2 blocks/CU):
//   [0,65536) B dbuf 2x32KB (A-scratch + ef bf16[64][258] overlay)
//   hn(neg) [65536,69632) lv [69632,70656)
//   idx [70656,70912) red [70912,70976)
// =====================================================================
#define HN_OFF   65536
#define LV_OFF   69632
#define IDX_OFF  70656
#define RED_OFF  70912
#define LDS_SZ   70976

__global__ __launch_bounds__(256, 2) void k1_fused(const float* __restrict__ z,
                                                   const float* __restrict__ cb,
                                                   const char* __restrict__ cbb,
                                                   const float* __restrict__ hn,
                                                   float* __restrict__ out,
                                                   float* __restrict__ pz2,
                                                   float* __restrict__ ps) {
  extern __shared__ char smem[];
  const int t = threadIdx.x, w = t >> 6, lane = t & 63;
  const int l15 = lane & 15, g4 = lane >> 4;
  const int wv = w;                 // wave = code-quarter owner
  const int bid = blockIdx.x;
  const int b = bid >> 6, hw0 = (bid & 63) << 6;
  const float* zb = z + ((size_t)b << 20) + hw0;

  // ---- A stage (R8/R11-verified): 64 rows x 256 ch, float4 loads ----
  const int q = t & 15, oslot = t >> 4;
  float ss = 0.f;
#pragma unroll 1
  for (int oi = 0; oi < 2; ++oi) {
    const int o = oslot + oi * 16;  // channel octet 0..31
    float4 f[8];
#pragma unroll
    for (int j = 0; j < 8; ++j)
      f[j] = *(const float4*)(zb + (size_t)(o * 8 + j) * 4096 + q * 4);
#pragma unroll
    for (int j = 0; j < 8; ++j)
      ss += f[j].x * f[j].x + f[j].y * f[j].y + f[j].z * f[j].z + f[j].w * f[j].w;
    const int kk = o >> 2, g = o & 3;
#pragma unroll
    for (int k = 0; k < 4; ++k) {
      const int row = q * 4 + k;
      const int band = row >> 5, rb = row & 31;
      const int mb = rb >> 4, r15 = rb & 15;
      uint4 q4;
      q4.x = f2bf(((const float*)&f[0])[k]) | (f2bf(((const float*)&f[1])[k]) << 16);
      q4.y = f2bf(((const float*)&f[2])[k]) | (f2bf(((const float*)&f[3])[k]) << 16);
      q4.z = f2bf(((const float*)&f[4])[k]) | (f2bf(((const float*)&f[5])[k]) << 16);
      q4.w = f2bf(((const float*)&f[6])[k]) | (f2bf(((const float*)&f[7])[k]) << 16);
      *(uint4*)(smem + (band << 14) + (((mb << 3) + kk) << 10) + (((g << 4) + r15) << 4)) = q4;
    }
  }
  // hn -> LDS NEGATED (MFMA C-init fold)
  {
    const float4 h = *(const float4*)(hn + 4 * t);
    float4 nh;
    nh.x = -h.x; nh.y = -h.y; nh.z = -h.z; nh.w = -h.w;
    *(float4*)(smem + HN_OFF + t * 16) = nh;
  }
  __syncthreads();

  // ---- A panel -> registers: FULL 64 rows (32 frags = 128 VGPR) ----
  bf16x8 A[4][8];
#pragma unroll
  for (int mb = 0; mb < 4; ++mb)
#pragma unroll
    for (int kk = 0; kk < 8; ++kk) {
      const int band = mb >> 1, mbb = mb & 1;
      A[mb][kk] = *(const bf16x8*)(smem + (band << 14) + (((mbb << 3) + kk) << 10) + (lane << 4));
    }
  __syncthreads();  // all waves done with scratch before B staging

  // ---- B stage: own quarter only, 8 issues/wave x 1 KB ----
  auto stageB = [&](int buf, int ch) {
#pragma unroll
    for (int i = 0; i < 8; ++i) {
      __builtin_amdgcn_global_load_lds(
          (const __attribute__((address_space(1))) unsigned int*)
              (cbb + ((size_t)ch << 15) + (wv << 13) + (i << 10) + (lane << 4)),
          (__attribute__((address_space(3))) unsigned int*)
              (smem + (buf << 15) + (wv << 13) + (i << 10)),
          16, 0, 0);
    }
  };
  stageB(0, 0);
  stageB(1, 1);

  const float* hn_s = (const float*)(smem + HN_OFF);
  float bestp[4][4];
#pragma unroll
  for (int m = 0; m < 4; ++m)
#pragma unroll
    for (int i = 0; i < 4; ++i) bestp[m][i] = -3.4e38f;

  // ---- barrier-free main loop: 16 chunks, own quarter only ----
  for (int ch = 0; ch < 16; ++ch) {
    const int cur = ch & 1;
    if (ch < 15) asm volatile("s_waitcnt vmcnt(8)" ::: "memory");
    else         asm volatile("s_waitcnt vmcnt(0)" ::: "memory");
    __builtin_amdgcn_sched_barrier(0);
    const int col = ch * 64 + wv * 16 + l15;
    const float nh = hn_s[col];
    f32x4v acc[4];
#pragma unroll
    for (int m = 0; m < 4; ++m) acc[m] = (f32x4v){nh, nh, nh, nh};
    __builtin_amdgcn_s_setprio(1);
#pragma unroll
    for (int kk = 0; kk < 8; ++kk) {
      const bf16x8 b0 = *(const bf16x8*)(smem + (cur << 15) + (wv << 13) +
                                         (kk << 10) + (lane << 4));
#pragma unroll
      for (int m = 0; m < 4; ++m)
        acc[m] = __builtin_amdgcn_mfma_f32_16x16x32_bf16(A[m][kk], b0, acc[m], 0, 0, 0);
    }
    __builtin_amdgcn_s_setprio(0);
    __builtin_amdgcn_sched_barrier(0);   // reads done (consumed) before restage
    if (ch + 2 < 16) stageB(cur, ch + 2);
    const unsigned int iv = 1023u - (unsigned int)col;
#pragma unroll
    for (int m = 0; m < 4; ++m)
#pragma unroll
      for (int i = 0; i < 4; ++i) {
        const unsigned int u = (__float_as_uint(acc[m][i]) & 0xFFFFFC00u) | iv;
        bestp[m][i] = fmaxf(bestp[m][i], __uint_as_float(u));
      }
  }

  // ---- cross-lane packed argmax within 16-col groups ----
#pragma unroll
  for (int m = 0; m < 4; ++m)
#pragma unroll
    for (int i = 0; i < 4; ++i) {
      float v = bestp[m][i];
#pragma unroll
      for (int s = 1; s < 16; s <<= 1)
        v = fmaxf(v, __shfl_xor(v, s, 64));
      bestp[m][i] = v;
    }

  float* lv = (float*)(smem + LV_OFF);
  int* idx_s = (int*)(smem + IDX_OFF);
  if (l15 == 0) {
#pragma unroll
    for (int m = 0; m < 4; ++m)
#pragma unroll
      for (int i = 0; i < 4; ++i) {
        const int row = m * 16 + g4 * 4 + i;
        lv[wv * 64 + row] = bestp[m][i];
      }
  }
  __syncthreads();
  float sv = 0.f;
  if (t < 64) {
    const float pm = fmaxf(fmaxf(lv[t], lv[64 + t]),
                           fmaxf(lv[128 + t], lv[192 + t]));
    const unsigned int ub = __float_as_uint(pm);
    idx_s[t] = 1023 - (int)(ub & 1023u);
    sv = __uint_as_float(ub & 0xFFFFFC00u);
  }
  // block reductions: pz2 = Sigma z^2 (exact cover), ps = Sigma s*
  float zz = ss;
#pragma unroll
  for (int s = 32; s; s >>= 1) {
    zz += __shfl_down(zz, s, 64);
    sv += __shfl_down(sv, s, 64);
  }
  float* red = (float*)(smem + RED_OFF);
  if (lane == 0) { red[w] = zz; red[4 + w] = sv; }
  __syncthreads();  // idx_s visible; B bufs dead -> ef may overlay
  if (t == 0) {
    pz2[bid] = red[0] + red[1] + red[2] + red[3];
    ps[bid] = red[4] + red[5] + red[6] + red[7];
  }

  // ---- epilogue: chosen rows -> bf16 ef [64][258] (R11-verified) ----
#pragma unroll 4
  for (int rr = 0; rr < 16; ++rr) {
    const int r = w * 16 + rr;
    const int code = idx_s[r];  // wave-uniform broadcast
    const float4 ev = *(const float4*)(cb + (size_t)code * 256 + lane * 4);
    uint2 p;
    p.x = f2bf(ev.x) | (f2bf(ev.y) << 16);
    p.y = f2bf(ev.z) | (f2bf(ev.w) << 16);
    *(uint2*)(smem + r * 516 + lane * 8) = p;
  }
  __syncthreads();
  // ---- b128 pair reads, f32x2 stores (rows r0,r0+1 contiguous) ----
  float* outb = out + ((size_t)b << 20) + hw0;
  const int l5 = lane & 31, chf = lane >> 5;
  const int c0e = w * 64 + chf * 32;
  const int r0 = l5 * 2;
#pragma unroll
  for (int i = 0; i < 4; ++i) {
    const uint4 u0 = *(const uint4*)(smem + r0 * 516 + (c0e + i * 8) * 2);
    const uint4 u1 = *(const uint4*)(smem + (r0 + 1) * 516 + (c0e + i * 8) * 2);
    const ushort* p0 = (const ushort*)&u0;
    const ushort* p1 = (const ushort*)&u1;
#pragma unroll
    for (int j = 0; j < 8; ++j) {
      const int c = c0e + i * 8 + j;
      f32x2v ov;
      ov[0] = __uint_as_float(((unsigned)p0[j]) << 16);
      ov[1] = __uint_as_float(((unsigned)p1[j]) << 16);
      __builtin_nontemporal_store(ov, (f32x2v*)(outb + (size_t)c * 4096 + r0));
    }
  }
}

// =====================================================================
// k3: deterministic reduce of 1024 block partials -> vq_loss
// =====================================================================
__global__ __launch_bounds__(256) void k3_loss(const float* __restrict__ pz2,
                                               const float* __restrict__ ps,
                                               float* __restrict__ loss_out) {
  __shared__ double red[256];
  const int t = threadIdx.x;
  double s = 0.0;
#pragma unroll
  for (int i = 0; i < 4; ++i)
    s += (double)pz2[t * 4 + i] - 2.0 * (double)ps[t * 4 + i];
  red[t] = s;
  __syncthreads();
  for (int st = 128; st; st >>= 1) {
    if (t < st) red[t] += red[t + st];
    __syncthreads();
  }
  if (t == 0) loss_out[0] = (float)(red[0] * (1.25 / 16777216.0));
}

// =====================================================================
extern "C" void kernel_launch(void* const* d_in, const int* in_sizes, int n_in,
                              void* d_out, int out_size, void* d_ws, size_t ws_size,
                              hipStream_t stream) {
  (void)in_sizes; (void)n_in; (void)out_size; (void)ws_size;
  const float* z = (const float*)d_in[0];
  const float* cb = (const float*)d_in[1];
  float* out = (float*)d_out;

  char* wsb = (char*)d_ws;
  char* cbb = wsb;                               // 524288 B (quarter-frag order)
  float* hn = (float*)(wsb + 524288);            //   4096 B
  float* pz2 = (float*)(wsb + 528384);           //   4096 B
  float* ps = (float*)(wsb + 532480);            //   4096 B

  (void)hipFuncSetAttribute((const void*)k1_fused,
                            hipFuncAttributeMaxDynamicSharedMemorySize, LDS_SZ);

  k0b_cb<<<dim3(1024), dim3(64), 0, stream>>>(cb, cbb, hn);
  k1_fused<<<dim3(1024), dim3(256), LDS_SZ, stream>>>(z, cb, cbb, hn, out, pz2, ps);
  k3_loss<<<dim3(1), dim3(256), 0, stream>>>(pz2, ps, out + 16777216);
}